// Round 16
// baseline (461.061 us; speedup 1.0000x reference)
//
#include <hip/hip_runtime.h>
#include <math.h>

#define TLEN 2048
#define EMB 1024
#define QKVD 3072
#define NROWS 4096
#define LOG2E 1.4426950408889634f

typedef unsigned short u16;
typedef unsigned int u32;
using frag_ab = __attribute__((ext_vector_type(8))) short;  // 8 bf16
using f32x4   = __attribute__((ext_vector_type(4))) float;

__device__ __forceinline__ u16 f2bf(float x) {
    u32 u = __builtin_bit_cast(u32, x);
    u = (u + 0x7FFFu + ((u >> 16) & 1u)) >> 16;
    return (u16)u;
}

__device__ __forceinline__ float bf2f(u16 h) {
    return __builtin_bit_cast(float, (u32)h << 16);
}

__device__ __forceinline__ u32 cvt_pk_bf16(float lo, float hi) {
    u32 r;
    asm("v_cvt_pk_bf16_f32 %0, %1, %2" : "=v"(r) : "v"(lo), "v"(hi));
    return r;
}

__device__ __forceinline__ float exp2_hw(float x) {
    float r;
    asm("v_exp_f32 %0, %1" : "=v"(r) : "v"(x));
    return r;
}

#define GLL16(g, l) __builtin_amdgcn_global_load_lds(                         \
    (const __attribute__((address_space(1))) void*)(g),                       \
    (__attribute__((address_space(3))) void*)(l), 16, 0, 0)

// ---------------------------------------------------------------------------
// prep: fused {fp32->bf16 convert} + {mask build} + {combine-counter reset}
// ---------------------------------------------------------------------------
__global__ __launch_bounds__(256)
void prep(const float* __restrict__ qa, const float* __restrict__ wqkv,
          const float* __restrict__ wout, u16* __restrict__ out,
          const float* __restrict__ am, const int* __restrict__ kpm,
          float* __restrict__ cm, int* __restrict__ flags,
          int* __restrict__ cnt)
{
    __shared__ int kt[64][65];
    __shared__ int s_any;
    const int tid = threadIdx.x;
    const int bid = blockIdx.x;
    if (bid < 4096) {
        int i = (bid * 256 + tid) * 8;
        const float* src;
        int off;
        if (i < 4194304)      { src = qa;   off = i; }
        else if (i < 7340032) { src = wqkv; off = i - 4194304; }
        else                  { src = wout; off = i - 7340032; }
        float4 x = *reinterpret_cast<const float4*>(src + off);
        float4 y = *reinterpret_cast<const float4*>(src + off + 4);
        union { u16 h[8]; uint4 v; } o;
        o.h[0] = f2bf(x.x); o.h[1] = f2bf(x.y); o.h[2] = f2bf(x.z); o.h[3] = f2bf(x.w);
        o.h[4] = f2bf(y.x); o.h[5] = f2bf(y.y); o.h[6] = f2bf(y.z); o.h[7] = f2bf(y.w);
        *reinterpret_cast<uint4*>(out + i) = o.v;
        return;
    }
    const int id2 = bid - 4096;
    if (id2 < 512 && tid == 0 && cnt) cnt[id2] = 0;   // reset combine counters
    const int s0 = (id2 & 31) * 64, t0 = (id2 >> 5) * 64;
    if (tid == 0) s_any = 0;
    #pragma unroll
    for (int u = 0; u < 4; ++u) {
        int idx = u * 256 + tid;
        int r  = idx >> 4;
        int cq = (idx & 15) * 4;
        int4 v = *reinterpret_cast<const int4*>(&kpm[(size_t)(s0 + r) * TLEN + t0 + cq]);
        kt[r][cq + 0] = v.x; kt[r][cq + 1] = v.y; kt[r][cq + 2] = v.z; kt[r][cq + 3] = v.w;
    }
    __syncthreads();
    float rbuf[4][4];
    int myany = 0;
    #pragma unroll
    for (int u = 0; u < 4; ++u) {
        int idx = u * 256 + tid;
        int r  = idx >> 4;
        int cq = (idx & 15) * 4;
        float4 a = *reinterpret_cast<const float4*>(&am[(size_t)(t0 + r) * TLEN + s0 + cq]);
        const float av[4] = {a.x, a.y, a.z, a.w};
        #pragma unroll
        for (int c = 0; c < 4; ++c) {
            float t = (av[c] == 0.0f) ? 0.0f : av[c] * -10000.0f;
            if (kt[cq + c][r] != 0) t = -INFINITY;
            rbuf[u][c] = t * LOG2E;
            myany |= (rbuf[u][c] != 0.0f);
        }
    }
    if (myany) s_any = 1;       // benign race, all write 1
    __syncthreads();
    if (s_any) {
        #pragma unroll
        for (int u = 0; u < 4; ++u) {
            int idx = u * 256 + tid;
            int r  = idx >> 4;
            int cq = (idx & 15) * 4;
            *reinterpret_cast<float4*>(&cm[(size_t)(t0 + r) * TLEN + s0 + cq]) =
                make_float4(rbuf[u][0], rbuf[u][1], rbuf[u][2], rbuf[u][3]);
        }
    }
    if (tid == 0) flags[id2] = s_any;
}

// ---------------------------------------------------------------------------
// bf16 MFMA GEMM (NT): 128 x (NF*32) tile, BK=32, 4 waves, 16x16x32 MFMA.
// OUT_MODE 2 (gemm1): Q/K bf16 into qkv; V written transposed into Vg.
// ---------------------------------------------------------------------------
template <int OUT_MODE, int NF>
__global__ __launch_bounds__(256)
void gemm_nt_mfma(const u16* __restrict__ A, const u16* __restrict__ B,
                  const float* __restrict__ bias, void* __restrict__ Cp,
                  u16* __restrict__ Vg, int M, int N, int K)
{
    constexpr int BN = NF * 32;
    __shared__ u16 As[128 * 32];
    __shared__ u16 Bs[BN * 32];
    const int tid  = threadIdx.x;
    const int lane = tid & 63;
    const int w    = tid >> 6;
    const int wr   = w >> 1, wc = w & 1;

    const int nbx = N / BN;
    const int id  = blockIdx.x;
    const int lin = (id & 7) * ((int)gridDim.x >> 3) + (id >> 3);
    const int bm = (lin / nbx) * 128, bn = (lin % nbx) * BN;

    f32x4 acc[4][NF];
    #pragma unroll
    for (int i = 0; i < 4; ++i)
        #pragma unroll
        for (int j = 0; j < NF; ++j)
            acc[i][j] = (f32x4){0.f, 0.f, 0.f, 0.f};

    const int srow = tid >> 2;
    const int skel = (tid & 3) * 8;
    const u16* Ag = A + (size_t)(bm + srow) * K + skel;
    const u16* Bg = B + (size_t)(bn + srow % BN) * K + skel;
    u16* Asl = As + srow * 32 + skel;
    u16* Bsl = Bs + (srow % BN) * 32 + skel;

    const int fr = lane & 15;
    const int fk = (lane >> 4) * 8;

    for (int k0 = 0; k0 < K; k0 += 32) {
        GLL16(Ag + k0, Asl);
        GLL16(Ag + (size_t)64 * K + k0, Asl + 64 * 32);
        GLL16(Bg + k0, Bsl);
        if constexpr (NF == 4) GLL16(Bg + (size_t)64 * K + k0, Bsl + 64 * 32);
        __syncthreads();
        frag_ab af[4], bfr[NF];
        #pragma unroll
        for (int mf = 0; mf < 4; ++mf)
            af[mf] = *reinterpret_cast<const frag_ab*>(&As[(wr * 64 + mf * 16 + fr) * 32 + fk]);
        #pragma unroll
        for (int nf = 0; nf < NF; ++nf)
            bfr[nf] = *reinterpret_cast<const frag_ab*>(
                &Bs[(wc * (NF * 16) + nf * 16 + fr) * 32 + fk]);
        #pragma unroll
        for (int mf = 0; mf < 4; ++mf)
            #pragma unroll
            for (int nf = 0; nf < NF; ++nf)
                acc[mf][nf] = __builtin_amdgcn_mfma_f32_16x16x32_bf16(af[mf], bfr[nf], acc[mf][nf], 0, 0, 0);
        __syncthreads();
    }

    const int col0 = bn + wc * (NF * 16) + fr;
    const int row0 = bm + wr * 64 + (lane >> 4) * 4;
    #pragma unroll
    for (int nf = 0; nf < NF; ++nf) {
        const int col = col0 + nf * 16;
        const float bv = bias[col];
        if constexpr (OUT_MODE == 0) {
            #pragma unroll
            for (int mf = 0; mf < 4; ++mf)
                #pragma unroll
                for (int i = 0; i < 4; ++i)
                    ((float*)Cp)[(size_t)(row0 + mf * 16 + i) * N + col] = acc[mf][nf][i] + bv;
        } else {
            // head split: col = h*192 + seg
            const u32 q6 = (u32)col >> 6;
            const u32 h = (q6 * 0xAAABu) >> 17;   // q6/3, exact for q6 < 2^15
            const int seg = col - (int)h * 192;
            if (seg < 128) {
                #pragma unroll
                for (int mf = 0; mf < 4; ++mf)
                    #pragma unroll
                    for (int i = 0; i < 4; ++i)
                        ((u16*)Cp)[(size_t)(row0 + mf * 16 + i) * N + col] =
                            f2bf(acc[mf][nf][i] + bv);
            } else {
                const int d = seg - 128;
                #pragma unroll
                for (int mf = 0; mf < 4; ++mf)
                    #pragma unroll
                    for (int i = 0; i < 4; ++i) {
                        const int row = row0 + mf * 16 + i;   // row = t*2 + b
                        Vg[(size_t)(((row & 1) * 16 + (int)h) * 64 + d) * TLEN + (row >> 1)] =
                            f2bf(acc[mf][nf][i] + bv);
                    }
            }
        }
    }
}

// ---------------------------------------------------------------------------
// MFMA flash attention v16: v15 structure (32KB smem, Q direct to regs,
// (512,6), s-split partials) + FUSED last-block combine: per (bh,tt) a
// device-scope counter; the second-finishing half reads both partials and
// writes the X2 tile itself. Order-independent (same result either way),
// device-scope fences per G16; counters reset each call by prep.
// smem: Ks[0]@0 | Ks[1]@8192 | Vt[0]@16384 | Vt[1]@24576   (32768 B)
// ---------------------------------------------------------------------------
#define SM_VT 16384

#define ATTN_STEP(CUR, NXT, IT, SLIM, SIN, SOUT)                              \
  {                                                                           \
    float vq[4][4];                                                           \
    _Pragma("unroll") for (int nf = 0; nf < 4; ++nf) {                        \
      _Pragma("unroll") for (int i = 0; i < 4; ++i) {                         \
        const float sv = SIN[nf][i];                                          \
        const float v = fmaf(SSCALE, sv, -24.0f);                             \
        vq[nf][i] = (sv == 0.0f) ? -INFINITY : v;                             \
      }                                                                       \
    }                                                                         \
    if (fmask & (1u << (IT))) {                                               \
      _Pragma("unroll") for (int nf = 0; nf < 4; ++nf) {                      \
        const float4 c4 = *reinterpret_cast<const float4*>(                   \
            &cm2[(size_t)rq * TLEN + (IT) * 64 + nf * 16 + 4 * fg]);          \
        vq[nf][0] += c4.x; vq[nf][1] += c4.y;                                 \
        vq[nf][2] += c4.z; vq[nf][3] += c4.w;                                 \
      }                                                                       \
    }                                                                         \
    float pv[4][4];                                                           \
    _Pragma("unroll") for (int nf = 0; nf < 4; ++nf) {                        \
      _Pragma("unroll") for (int i = 0; i < 4; ++i)                           \
        pv[nf][i] = exp2_hw(vq[nf][i]);                                       \
    }                                                                         \
    u32 pkA[4], pkB[4];                                                       \
    _Pragma("unroll") for (int nf = 0; nf < 4; ++nf) {                        \
      pkA[nf] = cvt_pk_bf16(pv[nf][0], pv[nf][1]);                            \
      pkB[nf] = cvt_pk_bf16(pv[nf][2], pv[nf][3]);                            \
    }                                                                         \
    __builtin_amdgcn_s_setprio(1);                                            \
    _Pragma("unroll") for (int ks = 0; ks < 2; ++ks) {                        \
      u32 d0 = pkA[2 * ks], d1 = pkB[2 * ks];                                 \
      u32 s0 = pkA[2 * ks + 1], s1 = pkB[2 * ks + 1];                         \
      asm("v_permlane32_swap_b32 %0, %1" : "+v"(d0), "+v"(s0));               \
      asm("v_permlane32_swap_b32 %0, %1" : "+v"(d1), "+v"(s1));               \
      const u32 sel0 = odd ? d0 : s0;                                         \
      const u32 sel1 = odd ? d1 : s1;                                         \
      const u32 r0_ = __builtin_amdgcn_ds_swizzle(sel0, 0x401F);              \
      const u32 r1_ = __builtin_amdgcn_ds_swizzle(sel1, 0x401F);              \
      union { u32 wq[4]; frag_ab f; } pau;                                    \
      pau.wq[0] = odd ? r0_ : d0;                                             \
      pau.wq[1] = odd ? r1_ : d1;                                             \
      pau.wq[2] = odd ? s0 : r0_;                                             \
      pau.wq[3] = odd ? s1 : r1_;                                             \
      _Pragma("unroll") for (int nf = 0; nf < 4; ++nf) {                      \
        frag_ab bv = *reinterpret_cast<const frag_ab*>(                       \
            smem + SM_VT + (CUR) * 8192 + nf * 2048 + (ks ? kb1 : kb0));      \
        oacc[nf] = __builtin_amdgcn_mfma_f32_16x16x32_bf16(pau.f, bv,         \
                                                           oacc[nf], 0, 0, 0); \
      }                                                                       \
      osum = __builtin_amdgcn_mfma_f32_16x16x32_bf16(pau.f, fones, osum,      \
                                                     0, 0, 0);                \
    }                                                                         \
    __builtin_amdgcn_s_setprio(0);                                            \
    asm volatile("s_waitcnt vmcnt(0)" ::: "memory");                          \
    __builtin_amdgcn_s_barrier();                                             \
    {                                                                         \
      const int itn = ((IT) + 2 < (SLIM)) ? (IT) + 2 : (SLIM) - 1;            \
      GLL16(kbase + (size_t)((itn * 64 + srow) * 2 + b) * QKVD + gsrc,        \
            smem + (CUR) * 8192 + tid * 16);                                  \
      GLL16(vgbase + (size_t)srow * TLEN + itn * 64 + gsrc,                   \
            smem + SM_VT + (CUR) * 8192 + tid * 16);                          \
    }                                                                         \
    _Pragma("unroll") for (int nf = 0; nf < 4; ++nf)                          \
      SOUT[nf] = (f32x4){0.f, 0.f, 0.f, 0.f};                                 \
    __builtin_amdgcn_s_setprio(1);                                            \
    _Pragma("unroll") for (int nf = 0; nf < 4; ++nf) {                        \
      _Pragma("unroll") for (int ks = 0; ks < 2; ++ks) {                      \
        frag_ab bk = *reinterpret_cast<const frag_ab*>(                       \
            smem + (NXT) * 8192 + nf * 2048 + (ks ? kb1 : kb0));              \
        SOUT[nf] = __builtin_amdgcn_mfma_f32_16x16x32_bf16(bk, aq[ks],        \
                                                           SOUT[nf], 0, 0, 0); \
      }                                                                       \
    }                                                                         \
    __builtin_amdgcn_s_setprio(0);                                            \
  }

template <int NHALF>
__global__ __launch_bounds__(512, 6)
void attn_mfma(const u16* __restrict__ qkv, const float* __restrict__ cm2,
               const int* __restrict__ flags, const u16* __restrict__ Vg,
               u16* __restrict__ X2, u16* __restrict__ opart,
               float* __restrict__ lpart, int* __restrict__ cnt)
{
    __shared__ __attribute__((aligned(16))) char smem[32768];
    __shared__ int s_done;

    const int tid  = threadIdx.x;
    const int lane = tid & 63;
    const int w    = tid >> 6;        // 0..7

    // XCD-chunk swizzle (grid = 512*NHALF, %8 == 0)
    const int id  = blockIdx.x;
    const int cpx = 64 * NHALF;
    const int lin = (id & 7) * cpx + (id >> 3);
    int bh, tt, half;
    if constexpr (NHALF == 2) {
        bh = lin >> 5;  tt = (lin & 31) >> 1;  half = lin & 1;
    } else {
        bh = lin >> 4;  tt = lin & 15;         half = 0;
    }
    const int b = bh >> 4, h = bh & 15;
    const int t0 = tt * 128;
    const int sb = half * (32 / NHALF);        // first s-tile
    const int slim = sb + 32 / NHALF;          // one past last s-tile

    const u16* kbase  = qkv + h * 192 + 64;
    const u16* vgbase = Vg + (size_t)bh * 64 * TLEN;

    const int srow = tid >> 3;        // 0..63
    const int sgl  = tid & 7;
    const int gsrc = ((sgl ^ (srow & 7)) & 7) * 8;   // pre-swizzled source col
    const int fr = lane & 15;
    const int fg = lane >> 4;
    const bool odd = (lane & 16) != 0;
    const int rq = t0 + w * 16 + fr;                 // this lane's softmax row

    // per-lane LDS byte offsets (nf-independent: 16 = 0 mod 8)
    const int kb0 = fr * 128 + (((fg) ^ (fr & 7)) & 7) * 16;
    const int kb1 = fr * 128 + (((4 + fg) ^ (fr & 7)) & 7) * 16;

    frag_ab fones;
    #pragma unroll
    for (int j = 0; j < 8; ++j) fones[j] = (short)0x3F80;

    // ---- mask-tile nonzero bitmask (per-wave: flag row = wave's 16 t-rows) ----
    const int* fl = flags + ((t0 >> 6) + (w >> 2)) * 32;
    int fv = 0;
    if (lane < 32) fv = fl[lane];
    const u32 fmask = (u32)__ballot(fv != 0);

    // ---- Q fragments directly from global ----
    frag_ab aq[2];
    {
        const u16* qrow = qkv + (size_t)(rq * 2 + b) * QKVD + h * 192;
        aq[0] = *reinterpret_cast<const frag_ab*>(qrow + fg * 8);
        aq[1] = *reinterpret_cast<const frag_ab*>(qrow + (4 + fg) * 8);
    }

    // ---- prologue: tiles sb, sb+1 K/V into buf0/buf1 (async GLL) ----
    GLL16(kbase + (size_t)((sb * 64 + srow) * 2 + b) * QKVD + gsrc, smem + tid * 16);
    GLL16(vgbase + (size_t)srow * TLEN + sb * 64 + gsrc, smem + SM_VT + tid * 16);
    GLL16(kbase + (size_t)(((sb + 1) * 64 + srow) * 2 + b) * QKVD + gsrc,
          smem + 8192 + tid * 16);
    GLL16(vgbase + (size_t)srow * TLEN + (sb + 1) * 64 + gsrc,
          smem + SM_VT + 8192 + tid * 16);
    __syncthreads();

    f32x4 oacc[4];
    #pragma unroll
    for (int nf = 0; nf < 4; ++nf) oacc[nf] = (f32x4){0.f, 0.f, 0.f, 0.f};
    f32x4 osum = (f32x4){0.f, 0.f, 0.f, 0.f};
    f32x4 saccA[4], saccB[4];

    const float SSCALE = 0.125f * LOG2E;

    // QK(sb) from Ks[0] -> saccA
    #pragma unroll
    for (int nf = 0; nf < 4; ++nf) saccA[nf] = (f32x4){0.f, 0.f, 0.f, 0.f};
    __builtin_amdgcn_s_setprio(1);
    #pragma unroll
    for (int nf = 0; nf < 4; ++nf) {
        #pragma unroll
        for (int ks = 0; ks < 2; ++ks) {
            frag_ab bk = *reinterpret_cast<const frag_ab*>(
                smem + nf * 2048 + (ks ? kb1 : kb0));
            saccA[nf] = __builtin_amdgcn_mfma_f32_16x16x32_bf16(bk, aq[ks],
                                                                saccA[nf], 0, 0, 0);
        }
    }
    __builtin_amdgcn_s_setprio(0);

    for (int it2 = sb; it2 < slim; it2 += 2) {
        ATTN_STEP(0, 1, it2, slim, saccA, saccB)
        ATTN_STEP(1, 0, it2 + 1, slim, saccB, saccA)
    }

    if constexpr (NHALF == 2) {
        // write partials (O bf16, l f32)
        const int pidx = (bh * 16 + tt) * 2 + half;
        u16* ob = opart + (size_t)pidx * 8192;
        #pragma unroll
        for (int i = 0; i < 4; ++i) {
            const int row = w * 16 + fg * 4 + i;
            #pragma unroll
            for (int nf = 0; nf < 4; ++nf)
                ob[row * 64 + nf * 16 + fr] = f2bf(oacc[nf][i]);
            if (fr == 0) lpart[pidx * 128 + row] = osum[i];
        }
        // last-block-combines: release, count, second finisher combines
        __threadfence();
        if (tid == 0) s_done = atomicAdd(&cnt[bh * 16 + tt], 1);
        __syncthreads();
        if (s_done == 1) {
            __threadfence();   // acquire: other half's partials visible
            const int p0 = (bh * 16 + tt) * 2;
            const int r = tid >> 2;             // 0..127
            const int dbase = (tid & 3) * 16;   // 0,16,32,48
            const u16* o0 = opart + (size_t)p0 * 8192 + r * 64 + dbase;
            const u16* o1 = o0 + 8192;
            const float inv = 1.f / (lpart[p0 * 128 + r] + lpart[(p0 + 1) * 128 + r]);
            const int t = tt * 128 + r;
            const int rout = ((t >= 1024) ? 2048 : 0) + 2 * (t & 1023) + b;
            u16* dst = X2 + (size_t)rout * EMB + h * 64 + dbase;
            #pragma unroll
            for (int j = 0; j < 2; ++j) {
                uint4 a = *reinterpret_cast<const uint4*>(o0 + j * 8);
                uint4 c = *reinterpret_cast<const uint4*>(o1 + j * 8);
                const u32 aw[4] = {a.x, a.y, a.z, a.w};
                const u32 cw[4] = {c.x, c.y, c.z, c.w};
                union { u16 hh[8]; uint4 v; } o;
                #pragma unroll
                for (int k = 0; k < 4; ++k) {
                    const float lo = (bf2f((u16)aw[k]) + bf2f((u16)cw[k])) * inv;
                    const float hi = (bf2f((u16)(aw[k] >> 16)) + bf2f((u16)(cw[k] >> 16))) * inv;
                    o.hh[2 * k]     = f2bf(lo);
                    o.hh[2 * k + 1] = f2bf(hi);
                }
                *reinterpret_cast<uint4*>(dst + j * 8) = o.v;
            }
        }
    } else {
        #pragma unroll
        for (int i = 0; i < 4; ++i) {
            const int t = t0 + w * 16 + fg * 4 + i;
            const int rout = ((t >= 1024) ? 2048 : 0) + 2 * (t & 1023) + b;
            const float inv = 1.f / osum[i];
            #pragma unroll
            for (int nf = 0; nf < 4; ++nf)
                X2[(size_t)rout * EMB + h * 64 + nf * 16 + fr] = f2bf(oacc[nf][i] * inv);
        }
    }
}

// ---------------------------------------------------------------------------
extern "C" void kernel_launch(void* const* d_in, const int* in_sizes, int n_in,
                              void* d_out, int out_size, void* d_ws, size_t ws_size,
                              hipStream_t stream)
{
    const float* query = (const float*)d_in[0];
    const float* am    = (const float*)d_in[3];
    const int*   kpm   = (const int*)d_in[4];
    const float* Wqkv  = (const float*)d_in[5];
    const float* bqkv  = (const float*)d_in[6];
    const float* Wout  = (const float*)d_in[7];
    const float* bout  = (const float*)d_in[8];
    float* out = (float*)d_out;

    char* ws = (char*)d_ws;
    u16*   qkv_bf  = (u16*)(ws);                        // 25165824 B
    u16*   x2_bf   = (u16*)(ws + 25165824);             //  8388608 B
    float* cmask   = (float*)(ws + 33554432);           // 16777216 B
    u16*   q_bf    = (u16*)(ws + 50331648);             //  8388608 B
    u16*   wqkv_bf = (u16*)(ws + 58720256);             //  6291456 B
    u16*   wout_bf = (u16*)(ws + 65011712);             //  2097152 B
    int*   flags   = (int*)(ws + 67108864);             //     4096 B
    u16*   v_tr    = (u16*)(ws + 67112960);             //  8388608 B
    u16*   opart   = (u16*)(ws + 75501568);             // 16777216 B
    float* lpart   = (float*)(ws + 92278784);           //   524288 B
    int*   cnt     = (int*)(ws + 92803072);             //     2048 B

    const bool split = ws_size >= 92805120u;

    prep<<<5120, 256, 0, stream>>>(query, Wqkv, Wout, q_bf, am, kpm, cmask, flags,
                                   split ? cnt : nullptr);

    gemm_nt_mfma<2, 4><<<768, 256, 0, stream>>>(q_bf, wqkv_bf, bqkv, qkv_bf,
                                                v_tr, NROWS, QKVD, EMB);
    if (split) {
        attn_mfma<2><<<1024, 512, 0, stream>>>(qkv_bf, cmask, flags, v_tr,
                                               x2_bf, opart, lpart, cnt);
    } else {
        attn_mfma<1><<<512, 512, 0, stream>>>(qkv_bf, cmask, flags, v_tr,
                                              x2_bf, nullptr, nullptr, nullptr);
    }
    gemm_nt_mfma<0, 2><<<512, 256, 0, stream>>>(x2_bf, wout_bf, bout, out,
                                                nullptr, NROWS, EMB, EMB);
}

// Round 17
// 129.941 us; speedup vs baseline: 3.5482x; 3.5482x over previous
//
#include <hip/hip_runtime.h>
#include <math.h>

#define TLEN 2048
#define EMB 1024
#define QKVD 3072
#define NROWS 4096
#define LOG2E 1.4426950408889634f

typedef unsigned short u16;
typedef unsigned int u32;
using frag_ab = __attribute__((ext_vector_type(8))) short;  // 8 bf16
using f32x4   = __attribute__((ext_vector_type(4))) float;

__device__ __forceinline__ u16 f2bf(float x) {
    u32 u = __builtin_bit_cast(u32, x);
    u = (u + 0x7FFFu + ((u >> 16) & 1u)) >> 16;
    return (u16)u;
}

__device__ __forceinline__ u32 cvt_pk_bf16(float lo, float hi) {
    u32 r;
    asm("v_cvt_pk_bf16_f32 %0, %1, %2" : "=v"(r) : "v"(lo), "v"(hi));
    return r;
}

__device__ __forceinline__ float exp2_hw(float x) {
    float r;
    asm("v_exp_f32 %0, %1" : "=v"(r) : "v"(x));
    return r;
}

#define GLL16(g, l) __builtin_amdgcn_global_load_lds(                         \
    (const __attribute__((address_space(1))) void*)(g),                       \
    (__attribute__((address_space(3))) void*)(l), 16, 0, 0)

// ---------------------------------------------------------------------------
// prep: fused {fp32->bf16 convert of query/Wqkv/Wout} + {combined mask build}
// ---------------------------------------------------------------------------
__global__ __launch_bounds__(256)
void prep(const float* __restrict__ qa, const float* __restrict__ wqkv,
          const float* __restrict__ wout, u16* __restrict__ out,
          const float* __restrict__ am, const int* __restrict__ kpm,
          float* __restrict__ cm, int* __restrict__ flags)
{
    __shared__ int kt[64][65];
    __shared__ int s_any;
    const int tid = threadIdx.x;
    const int bid = blockIdx.x;
    if (bid < 4096) {
        int i = (bid * 256 + tid) * 8;
        const float* src;
        int off;
        if (i < 4194304)      { src = qa;   off = i; }
        else if (i < 7340032) { src = wqkv; off = i - 4194304; }
        else                  { src = wout; off = i - 7340032; }
        float4 x = *reinterpret_cast<const float4*>(src + off);
        float4 y = *reinterpret_cast<const float4*>(src + off + 4);
        union { u16 h[8]; uint4 v; } o;
        o.h[0] = f2bf(x.x); o.h[1] = f2bf(x.y); o.h[2] = f2bf(x.z); o.h[3] = f2bf(x.w);
        o.h[4] = f2bf(y.x); o.h[5] = f2bf(y.y); o.h[6] = f2bf(y.z); o.h[7] = f2bf(y.w);
        *reinterpret_cast<uint4*>(out + i) = o.v;
        return;
    }
    const int id2 = bid - 4096;
    const int s0 = (id2 & 31) * 64, t0 = (id2 >> 5) * 64;
    if (tid == 0) s_any = 0;
    #pragma unroll
    for (int u = 0; u < 4; ++u) {
        int idx = u * 256 + tid;
        int r  = idx >> 4;
        int cq = (idx & 15) * 4;
        int4 v = *reinterpret_cast<const int4*>(&kpm[(size_t)(s0 + r) * TLEN + t0 + cq]);
        kt[r][cq + 0] = v.x; kt[r][cq + 1] = v.y; kt[r][cq + 2] = v.z; kt[r][cq + 3] = v.w;
    }
    __syncthreads();
    float rbuf[4][4];
    int myany = 0;
    #pragma unroll
    for (int u = 0; u < 4; ++u) {
        int idx = u * 256 + tid;
        int r  = idx >> 4;
        int cq = (idx & 15) * 4;
        float4 a = *reinterpret_cast<const float4*>(&am[(size_t)(t0 + r) * TLEN + s0 + cq]);
        const float av[4] = {a.x, a.y, a.z, a.w};
        #pragma unroll
        for (int c = 0; c < 4; ++c) {
            float t = (av[c] == 0.0f) ? 0.0f : av[c] * -10000.0f;
            if (kt[cq + c][r] != 0) t = -INFINITY;
            rbuf[u][c] = t * LOG2E;
            myany |= (rbuf[u][c] != 0.0f);
        }
    }
    if (myany) s_any = 1;       // benign race, all write 1
    __syncthreads();
    if (s_any) {
        #pragma unroll
        for (int u = 0; u < 4; ++u) {
            int idx = u * 256 + tid;
            int r  = idx >> 4;
            int cq = (idx & 15) * 4;
            *reinterpret_cast<float4*>(&cm[(size_t)(t0 + r) * TLEN + s0 + cq]) =
                make_float4(rbuf[u][0], rbuf[u][1], rbuf[u][2], rbuf[u][3]);
        }
    }
    if (tid == 0) flags[id2] = s_any;
}

// ---------------------------------------------------------------------------
// bf16 MFMA GEMM (NT): 128 x (NF*32) tile, BK=32, 4 waves, 16x16x32 MFMA.
// OUT_MODE 2 (gemm1): Q/K bf16 into qkv; V written transposed into Vg.
// ---------------------------------------------------------------------------
template <int OUT_MODE, int NF>
__global__ __launch_bounds__(256)
void gemm_nt_mfma(const u16* __restrict__ A, const u16* __restrict__ B,
                  const float* __restrict__ bias, void* __restrict__ Cp,
                  u16* __restrict__ Vg, int M, int N, int K)
{
    constexpr int BN = NF * 32;
    __shared__ u16 As[128 * 32];
    __shared__ u16 Bs[BN * 32];
    const int tid  = threadIdx.x;
    const int lane = tid & 63;
    const int w    = tid >> 6;
    const int wr   = w >> 1, wc = w & 1;

    const int nbx = N / BN;
    const int id  = blockIdx.x;
    const int lin = (id & 7) * ((int)gridDim.x >> 3) + (id >> 3);
    const int bm = (lin / nbx) * 128, bn = (lin % nbx) * BN;

    f32x4 acc[4][NF];
    #pragma unroll
    for (int i = 0; i < 4; ++i)
        #pragma unroll
        for (int j = 0; j < NF; ++j)
            acc[i][j] = (f32x4){0.f, 0.f, 0.f, 0.f};

    const int srow = tid >> 2;
    const int skel = (tid & 3) * 8;
    const u16* Ag = A + (size_t)(bm + srow) * K + skel;
    const u16* Bg = B + (size_t)(bn + srow % BN) * K + skel;
    u16* Asl = As + srow * 32 + skel;
    u16* Bsl = Bs + (srow % BN) * 32 + skel;

    const int fr = lane & 15;
    const int fk = (lane >> 4) * 8;

    for (int k0 = 0; k0 < K; k0 += 32) {
        GLL16(Ag + k0, Asl);
        GLL16(Ag + (size_t)64 * K + k0, Asl + 64 * 32);
        GLL16(Bg + k0, Bsl);
        if constexpr (NF == 4) GLL16(Bg + (size_t)64 * K + k0, Bsl + 64 * 32);
        __syncthreads();
        frag_ab af[4], bfr[NF];
        #pragma unroll
        for (int mf = 0; mf < 4; ++mf)
            af[mf] = *reinterpret_cast<const frag_ab*>(&As[(wr * 64 + mf * 16 + fr) * 32 + fk]);
        #pragma unroll
        for (int nf = 0; nf < NF; ++nf)
            bfr[nf] = *reinterpret_cast<const frag_ab*>(
                &Bs[(wc * (NF * 16) + nf * 16 + fr) * 32 + fk]);
        #pragma unroll
        for (int mf = 0; mf < 4; ++mf)
            #pragma unroll
            for (int nf = 0; nf < NF; ++nf)
                acc[mf][nf] = __builtin_amdgcn_mfma_f32_16x16x32_bf16(af[mf], bfr[nf], acc[mf][nf], 0, 0, 0);
        __syncthreads();
    }

    const int col0 = bn + wc * (NF * 16) + fr;
    const int row0 = bm + wr * 64 + (lane >> 4) * 4;
    #pragma unroll
    for (int nf = 0; nf < NF; ++nf) {
        const int col = col0 + nf * 16;
        const float bv = bias[col];
        if constexpr (OUT_MODE == 0) {
            #pragma unroll
            for (int mf = 0; mf < 4; ++mf)
                #pragma unroll
                for (int i = 0; i < 4; ++i)
                    ((float*)Cp)[(size_t)(row0 + mf * 16 + i) * N + col] = acc[mf][nf][i] + bv;
        } else {
            // head split: col = h*192 + seg
            const u32 q6 = (u32)col >> 6;
            const u32 h = (q6 * 0xAAABu) >> 17;   // q6/3, exact for q6 < 2^15
            const int seg = col - (int)h * 192;
            if (seg < 128) {
                #pragma unroll
                for (int mf = 0; mf < 4; ++mf)
                    #pragma unroll
                    for (int i = 0; i < 4; ++i)
                        ((u16*)Cp)[(size_t)(row0 + mf * 16 + i) * N + col] =
                            f2bf(acc[mf][nf][i] + bv);
            } else {
                const int d = seg - 128;
                #pragma unroll
                for (int mf = 0; mf < 4; ++mf)
                    #pragma unroll
                    for (int i = 0; i < 4; ++i) {
                        const int row = row0 + mf * 16 + i;   // row = t*2 + b
                        Vg[(size_t)(((row & 1) * 16 + (int)h) * 64 + d) * TLEN + (row >> 1)] =
                            f2bf(acc[mf][nf][i] + bv);
                    }
            }
        }
    }
}

// ---------------------------------------------------------------------------
// MFMA flash attention v17 (consolidated best): QBLK=128, 8 waves (512 thr),
// Q fragments directly global->regs (no Q LDS), smem 32KB, (512,6) no-spill,
// full s-loop per block (no split -> no combine dispatch, no fences: R16's
// per-block __threadfence was catastrophic), direct X2 write.
// smem: Ks[0]@0 | Ks[1]@8192 | Vt[0]@16384 | Vt[1]@24576   (32768 B)
// ---------------------------------------------------------------------------
#define SM_VT 16384

#define ATTN_STEP(CUR, NXT, IT, SIN, SOUT)                                    \
  {                                                                           \
    float vq[4][4];                                                           \
    _Pragma("unroll") for (int nf = 0; nf < 4; ++nf) {                        \
      _Pragma("unroll") for (int i = 0; i < 4; ++i) {                         \
        const float sv = SIN[nf][i];                                          \
        const float v = fmaf(SSCALE, sv, -24.0f);                             \
        vq[nf][i] = (sv == 0.0f) ? -INFINITY : v;                             \
      }                                                                       \
    }                                                                         \
    if (fmask & (1u << (IT))) {                                               \
      _Pragma("unroll") for (int nf = 0; nf < 4; ++nf) {                      \
        const float4 c4 = *reinterpret_cast<const float4*>(                   \
            &cm2[(size_t)rq * TLEN + (IT) * 64 + nf * 16 + 4 * fg]);          \
        vq[nf][0] += c4.x; vq[nf][1] += c4.y;                                 \
        vq[nf][2] += c4.z; vq[nf][3] += c4.w;                                 \
      }                                                                       \
    }                                                                         \
    float pv[4][4];                                                           \
    _Pragma("unroll") for (int nf = 0; nf < 4; ++nf) {                        \
      _Pragma("unroll") for (int i = 0; i < 4; ++i)                           \
        pv[nf][i] = exp2_hw(vq[nf][i]);                                       \
    }                                                                         \
    u32 pkA[4], pkB[4];                                                       \
    _Pragma("unroll") for (int nf = 0; nf < 4; ++nf) {                        \
      pkA[nf] = cvt_pk_bf16(pv[nf][0], pv[nf][1]);                            \
      pkB[nf] = cvt_pk_bf16(pv[nf][2], pv[nf][3]);                            \
    }                                                                         \
    __builtin_amdgcn_s_setprio(1);                                            \
    _Pragma("unroll") for (int ks = 0; ks < 2; ++ks) {                        \
      u32 d0 = pkA[2 * ks], d1 = pkB[2 * ks];                                 \
      u32 s0 = pkA[2 * ks + 1], s1 = pkB[2 * ks + 1];                         \
      asm("v_permlane32_swap_b32 %0, %1" : "+v"(d0), "+v"(s0));               \
      asm("v_permlane32_swap_b32 %0, %1" : "+v"(d1), "+v"(s1));               \
      const u32 sel0 = odd ? d0 : s0;                                         \
      const u32 sel1 = odd ? d1 : s1;                                         \
      const u32 r0_ = __builtin_amdgcn_ds_swizzle(sel0, 0x401F);              \
      const u32 r1_ = __builtin_amdgcn_ds_swizzle(sel1, 0x401F);              \
      union { u32 wq[4]; frag_ab f; } pau;                                    \
      pau.wq[0] = odd ? r0_ : d0;                                             \
      pau.wq[1] = odd ? r1_ : d1;                                             \
      pau.wq[2] = odd ? s0 : r0_;                                             \
      pau.wq[3] = odd ? s1 : r1_;                                             \
      _Pragma("unroll") for (int nf = 0; nf < 4; ++nf) {                      \
        frag_ab bv = *reinterpret_cast<const frag_ab*>(                       \
            smem + SM_VT + (CUR) * 8192 + nf * 2048 + (ks ? kb1 : kb0));      \
        oacc[nf] = __builtin_amdgcn_mfma_f32_16x16x32_bf16(pau.f, bv,         \
                                                           oacc[nf], 0, 0, 0); \
      }                                                                       \
      osum = __builtin_amdgcn_mfma_f32_16x16x32_bf16(pau.f, fones, osum,      \
                                                     0, 0, 0);                \
    }                                                                         \
    __builtin_amdgcn_s_setprio(0);                                            \
    asm volatile("s_waitcnt vmcnt(0)" ::: "memory");                          \
    __builtin_amdgcn_s_barrier();                                             \
    {                                                                         \
      const int itn = ((IT) + 2 < 32) ? (IT) + 2 : 31;                        \
      GLL16(kbase + (size_t)((itn * 64 + srow) * 2 + b) * QKVD + gsrc,        \
            smem + (CUR) * 8192 + tid * 16);                                  \
      GLL16(vgbase + (size_t)srow * TLEN + itn * 64 + gsrc,                   \
            smem + SM_VT + (CUR) * 8192 + tid * 16);                          \
    }                                                                         \
    _Pragma("unroll") for (int nf = 0; nf < 4; ++nf)                          \
      SOUT[nf] = (f32x4){0.f, 0.f, 0.f, 0.f};                                 \
    __builtin_amdgcn_s_setprio(1);                                            \
    _Pragma("unroll") for (int nf = 0; nf < 4; ++nf) {                        \
      _Pragma("unroll") for (int ks = 0; ks < 2; ++ks) {                      \
        frag_ab bk = *reinterpret_cast<const frag_ab*>(                       \
            smem + (NXT) * 8192 + nf * 2048 + (ks ? kb1 : kb0));              \
        SOUT[nf] = __builtin_amdgcn_mfma_f32_16x16x32_bf16(bk, aq[ks],        \
                                                           SOUT[nf], 0, 0, 0); \
      }                                                                       \
    }                                                                         \
    __builtin_amdgcn_s_setprio(0);                                            \
  }

__global__ __launch_bounds__(512, 6)
void attn_mfma(const u16* __restrict__ qkv, const float* __restrict__ cm2,
               const int* __restrict__ flags, const u16* __restrict__ Vg,
               u16* __restrict__ X2)
{
    __shared__ __attribute__((aligned(16))) char smem[32768];

    const int tid  = threadIdx.x;
    const int lane = tid & 63;
    const int w    = tid >> 6;        // 0..7

    // XCD-chunk swizzle (512 blocks, 64 per XCD = 4 bh x 16 t-tiles)
    const int id  = blockIdx.x;
    const int lin = (id & 7) * 64 + (id >> 3);
    const int bh  = lin >> 4;
    const int tt  = lin & 15;
    const int b = bh >> 4, h = bh & 15;
    const int t0 = tt * 128;

    const u16* kbase  = qkv + h * 192 + 64;
    const u16* vgbase = Vg + (size_t)bh * 64 * TLEN;

    const int srow = tid >> 3;        // 0..63
    const int sgl  = tid & 7;
    const int gsrc = ((sgl ^ (srow & 7)) & 7) * 8;   // pre-swizzled source col
    const int fr = lane & 15;
    const int fg = lane >> 4;
    const bool odd = (lane & 16) != 0;
    const int rq = t0 + w * 16 + fr;                 // this lane's softmax row

    // per-lane LDS byte offsets (nf-independent: 16 = 0 mod 8)
    const int kb0 = fr * 128 + (((fg) ^ (fr & 7)) & 7) * 16;
    const int kb1 = fr * 128 + (((4 + fg) ^ (fr & 7)) & 7) * 16;

    frag_ab fones;
    #pragma unroll
    for (int j = 0; j < 8; ++j) fones[j] = (short)0x3F80;

    // ---- mask-tile nonzero bitmask (per-wave: flag row = wave's 16 t-rows) ----
    const int* fl = flags + ((t0 >> 6) + (w >> 2)) * 32;
    int fv = 0;
    if (lane < 32) fv = fl[lane];
    const u32 fmask = (u32)__ballot(fv != 0);

    // ---- Q fragments directly from global (swizzle was LDS-banking only) ----
    frag_ab aq[2];
    {
        const u16* qrow = qkv + (size_t)(rq * 2 + b) * QKVD + h * 192;
        aq[0] = *reinterpret_cast<const frag_ab*>(qrow + fg * 8);
        aq[1] = *reinterpret_cast<const frag_ab*>(qrow + (4 + fg) * 8);
    }

    // ---- prologue: tiles 0, 1 K/V into buf0/buf1 (async GLL) ----
    GLL16(kbase + (size_t)(srow * 2 + b) * QKVD + gsrc, smem + tid * 16);
    GLL16(vgbase + (size_t)srow * TLEN + gsrc, smem + SM_VT + tid * 16);
    GLL16(kbase + (size_t)((64 + srow) * 2 + b) * QKVD + gsrc, smem + 8192 + tid * 16);
    GLL16(vgbase + (size_t)srow * TLEN + 64 + gsrc, smem + SM_VT + 8192 + tid * 16);
    __syncthreads();

    f32x4 oacc[4];
    #pragma unroll
    for (int nf = 0; nf < 4; ++nf) oacc[nf] = (f32x4){0.f, 0.f, 0.f, 0.f};
    f32x4 osum = (f32x4){0.f, 0.f, 0.f, 0.f};
    f32x4 saccA[4], saccB[4];

    const float SSCALE = 0.125f * LOG2E;

    // QK(0) from Ks[0] -> saccA
    #pragma unroll
    for (int nf = 0; nf < 4; ++nf) saccA[nf] = (f32x4){0.f, 0.f, 0.f, 0.f};
    __builtin_amdgcn_s_setprio(1);
    #pragma unroll
    for (int nf = 0; nf < 4; ++nf) {
        #pragma unroll
        for (int ks = 0; ks < 2; ++ks) {
            frag_ab bk = *reinterpret_cast<const frag_ab*>(
                smem + nf * 2048 + (ks ? kb1 : kb0));
            saccA[nf] = __builtin_amdgcn_mfma_f32_16x16x32_bf16(bk, aq[ks],
                                                                saccA[nf], 0, 0, 0);
        }
    }
    __builtin_amdgcn_s_setprio(0);

    for (int it2 = 0; it2 < 32; it2 += 2) {
        ATTN_STEP(0, 1, it2, saccA, saccB)
        ATTN_STEP(1, 0, it2 + 1, saccB, saccA)
    }

    // epilogue: osum[i] is the row sum for row fg*4+i (same layout as oacc)
    #pragma unroll
    for (int i = 0; i < 4; ++i) {
        const int t = t0 + w * 16 + fg * 4 + i;
        const int rout = ((t >= 1024) ? 2048 : 0) + 2 * (t & 1023) + b;
        const float inv = 1.f / osum[i];
        #pragma unroll
        for (int nf = 0; nf < 4; ++nf)
            X2[(size_t)rout * EMB + h * 64 + nf * 16 + fr] = f2bf(oacc[nf][i] * inv);
    }
}

// ---------------------------------------------------------------------------
extern "C" void kernel_launch(void* const* d_in, const int* in_sizes, int n_in,
                              void* d_out, int out_size, void* d_ws, size_t ws_size,
                              hipStream_t stream)
{
    const float* query = (const float*)d_in[0];
    const float* am    = (const float*)d_in[3];
    const int*   kpm   = (const int*)d_in[4];
    const float* Wqkv  = (const float*)d_in[5];
    const float* bqkv  = (const float*)d_in[6];
    const float* Wout  = (const float*)d_in[7];
    const float* bout  = (const float*)d_in[8];
    float* out = (float*)d_out;

    char* ws = (char*)d_ws;
    u16*   qkv_bf  = (u16*)(ws);                        // 25165824 B
    u16*   x2_bf   = (u16*)(ws + 25165824);             //  8388608 B
    float* cmask   = (float*)(ws + 33554432);           // 16777216 B
    u16*   q_bf    = (u16*)(ws + 50331648);             //  8388608 B
    u16*   wqkv_bf = (u16*)(ws + 58720256);             //  6291456 B
    u16*   wout_bf = (u16*)(ws + 65011712);             //  2097152 B
    int*   flags   = (int*)(ws + 67108864);             //     4096 B
    u16*   v_tr    = (u16*)(ws + 67112960);             //  8388608 B

    prep<<<5120, 256, 0, stream>>>(query, Wqkv, Wout, q_bf, am, kpm, cmask, flags);

    gemm_nt_mfma<2, 4><<<768, 256, 0, stream>>>(q_bf, wqkv_bf, bqkv, qkv_bf,
                                                v_tr, NROWS, QKVD, EMB);
    attn_mfma<<<512, 512, 0, stream>>>(qkv_bf, cmask, flags, v_tr, x2_bf);
    gemm_nt_mfma<0, 2><<<512, 256, 0, stream>>>(x2_bf, wout_bf, bout, out,
                                                nullptr, NROWS, EMB, EMB);
}